// Round 6
// baseline (237.656 us; speedup 1.0000x reference)
//
#include <hip/hip_runtime.h>
#include <hip/hip_fp16.h>

static constexpr int Hh = 384;
static constexpr int Ww = 1280;
static constexpr int HW = Hh * Ww;            // 491520
static constexpr int NPIX = 2 * HW;           // 983040
static constexpr int TILE = 32;               // output tile side
static constexpr int S = 8;                   // fused Jacobi steps per launch
static constexpr int R = TILE + 2 * S;        // 48: region side incl. halo
static constexpr int RR = R * R;              // 2304
static constexpr int BLOCK = 320;             // 5 waves; 288 compute threads
static constexpr int CT = RR / 8;             // 288 threads x 8 consecutive px
static constexpr int TI = Hh / TILE;          // 12
static constexpr int TJ = Ww / TILE;          // 40
static constexpr int GRID = 2 * TI * TJ;      // 960 tiles
static constexpr float EPSF = 1e-9f;

// k order matches reference PADS: (di,dj) =
// k:   0       1       2       3       4       5       6       7
//    (+1,+1) (+1,0) (+1,-1) (0,+1) (0,-1) (-1,+1) (-1,0) (-1,-1)
__device__ __constant__ int DI_c[8] = { 1, 1, 1, 0, 0, -1, -1, -1 };
__device__ __constant__ int DJ_c[8] = { 1, 0, -1, 1, -1, 1, 0, -1 };

// Precompute per pixel: w'_k (fp16, zeroed where sparse-clamped) and
// C = m ? raw : (1-gate_sum)*raw. Each step is then d' = C + sum w'_k d_k.
__global__ void affinity_norm(const float* __restrict__ g,
                              const float* __restrict__ raw,
                              const float* __restrict__ sparse,
                              __half* __restrict__ wbuf,
                              float* __restrict__ cbuf) {
    int idx = blockIdx.x * blockDim.x + threadIdx.x;
    if (idx >= NPIX) return;
    int b = idx / HW;
    int r = idx - b * HW;
    int i = r / Ww;
    int j = r - i * Ww;

    const float* gb = g + (size_t)b * 8 * HW;
    float v[8];
    float a = EPSF;
#pragma unroll
    for (int k = 0; k < 8; k++) {
        int ii = i + DI_c[k], jj = j + DJ_c[k];
        float gv = 0.0f;
        if (ii >= 0 && ii < Hh && jj >= 0 && jj < Ww)
            gv = gb[k * HW + ii * Ww + jj];
        v[k] = gv;
        a += fabsf(gv);
    }
    float inv = 1.0f / a, gs = 0.0f;
#pragma unroll
    for (int k = 0; k < 8; k++) { v[k] *= inv; gs += v[k]; }

    float rawv = raw[idx];
    bool m = sparse[idx] > 0.0f;   // sparse >= 0 always; sign(s)==1 iff s>0
    cbuf[idx] = m ? rawv : (1.0f - gs) * rawv;
    __half wv[8];
#pragma unroll
    for (int k = 0; k < 8; k++) wv[k] = __float2half(m ? 0.0f : v[k]);
    *(float4*)(wbuf + (size_t)idx * 8) = *(const float4*)wv;
}

// Fused S=8 Jacobi steps. Block owns a 48x48 region (32x32 valid center,
// halo 8). Thread ct<288 owns 8 consecutive px of one region row; its 8x
// fp16 weights + C stay in registers all S steps; d ping-pongs in LDS with
// float4 window loads. Ring/OOB px get w=0, C=d0 -> copy forward branchlessly
// (clamped window indices only ever feed w==0 pixels).
__global__ __launch_bounds__(BLOCK, 5) void fused_steps(
    const __half* __restrict__ wbuf, const float* __restrict__ cbuf,
    const float* __restrict__ din, float* __restrict__ dout)
{
    __shared__ float sd[2][RR];

    const int tid = threadIdx.x;
    int bx = blockIdx.x;
    const int tj = bx % TJ; bx /= TJ;
    const int ti = bx % TI;
    const int b  = bx / TI;
    const int oi = ti * TILE - S;          // region origin (image coords)
    const int oj = tj * TILE - S;

    const bool active = tid < CT;
    const int r  = tid / 6;                // region row   (0..47)
    const int c8 = (tid % 6) * 8;          // segment col  {0,8,...,40}

    float4 wreg[8];                        // 8 px x 8 fp16 weights
    float  C[8];

    // --- stage d0 / w / C ---
    if (active) {
        float d0[8];
        const int gi  = oi + r;
        const int gic = min(max(gi, 0), Hh - 1);
        const bool rring = (r == 0) | (r == R - 1) | (gi != gic);
#pragma unroll
        for (int i = 0; i < 8; i++) {
            const int cc  = c8 + i;
            const int gj  = oj + cc;
            const int gjc = min(max(gj, 0), Ww - 1);
            const int idx = b * HW + gic * Ww + gjc;
            float dv = din[idx];
            d0[i] = dv;
            wreg[i] = *(const float4*)(wbuf + (size_t)idx * 8);
            C[i]    = cbuf[idx];
            if (rring | (cc == 0) | (cc == R - 1) | (gj != gjc)) {
                wreg[i] = make_float4(0.f, 0.f, 0.f, 0.f);
                C[i] = dv;
            }
        }
        *(float4*)&sd[0][r * R + c8]     = make_float4(d0[0], d0[1], d0[2], d0[3]);
        *(float4*)&sd[0][r * R + c8 + 4] = make_float4(d0[4], d0[5], d0[6], d0[7]);
    }
    __syncthreads();

    const int rm = max(r - 1, 0) * R;
    const int r0 = r * R;
    const int rp = min(r + 1, R - 1) * R;
    const int cl = max(c8 - 1, 0);          // clamped window ends only feed
    const int cr = min(c8 + 8, R - 1);      // ring px (w==0), so safe

    // --- steps 1..S-1 over the full region, in LDS ---
    int cur = 0;
    for (int s = 1; s < S; s++) {
        const float* s0 = sd[cur];
        float* s1 = sd[cur ^ 1];
        if (active) {
            float wm[10], w0_[10], wp[10];
            wm[0]  = s0[rm + cl];  *(float4*)&wm[1]  = *(const float4*)&s0[rm + c8];
            *(float4*)&wm[5]  = *(const float4*)&s0[rm + c8 + 4];  wm[9]  = s0[rm + cr];
            w0_[0] = s0[r0 + cl];  *(float4*)&w0_[1] = *(const float4*)&s0[r0 + c8];
            *(float4*)&w0_[5] = *(const float4*)&s0[r0 + c8 + 4];  w0_[9] = s0[r0 + cr];
            wp[0]  = s0[rp + cl];  *(float4*)&wp[1]  = *(const float4*)&s0[rp + c8];
            *(float4*)&wp[5]  = *(const float4*)&s0[rp + c8 + 4];  wp[9]  = s0[rp + cr];

            float acc[8];
#pragma unroll
            for (int i = 0; i < 8; i++) {
                const __half2* wh = (const __half2*)&wreg[i];
                float2 w01 = __half22float2(wh[0]);
                float2 w23 = __half22float2(wh[1]);
                float2 w45 = __half22float2(wh[2]);
                float2 w67 = __half22float2(wh[3]);
                acc[i] = C[i]
                       + w01.x * wp[i + 2] + w01.y * wp[i + 1] + w23.x * wp[i]
                       + w23.y * w0_[i + 2] + w45.x * w0_[i]
                       + w45.y * wm[i + 2] + w67.x * wm[i + 1] + w67.y * wm[i];
            }
            *(float4*)&s1[r0 + c8]     = make_float4(acc[0], acc[1], acc[2], acc[3]);
            *(float4*)&s1[r0 + c8 + 4] = make_float4(acc[4], acc[5], acc[6], acc[7]);
        }
        __syncthreads();
        cur ^= 1;
    }

    // --- final step: valid 32x32 center only, straight to global ---
    const float* s0 = sd[cur];
    if (active && r >= S && r < R - S && c8 >= 8 && c8 < 40) {
        float wm[10], w0_[10], wp[10];
        wm[0]  = s0[rm + cl];  *(float4*)&wm[1]  = *(const float4*)&s0[rm + c8];
        *(float4*)&wm[5]  = *(const float4*)&s0[rm + c8 + 4];  wm[9]  = s0[rm + cr];
        w0_[0] = s0[r0 + cl];  *(float4*)&w0_[1] = *(const float4*)&s0[r0 + c8];
        *(float4*)&w0_[5] = *(const float4*)&s0[r0 + c8 + 4];  w0_[9] = s0[r0 + cr];
        wp[0]  = s0[rp + cl];  *(float4*)&wp[1]  = *(const float4*)&s0[rp + c8];
        *(float4*)&wp[5]  = *(const float4*)&s0[rp + c8 + 4];  wp[9]  = s0[rp + cr];

        float acc[8];
#pragma unroll
        for (int i = 0; i < 8; i++) {
            const __half2* wh = (const __half2*)&wreg[i];
            float2 w01 = __half22float2(wh[0]);
            float2 w23 = __half22float2(wh[1]);
            float2 w45 = __half22float2(wh[2]);
            float2 w67 = __half22float2(wh[3]);
            acc[i] = C[i]
                   + w01.x * wp[i + 2] + w01.y * wp[i + 1] + w23.x * wp[i]
                   + w23.y * w0_[i + 2] + w45.x * w0_[i]
                   + w45.y * wm[i + 2] + w67.x * wm[i + 1] + w67.y * wm[i];
        }
        const int gi = oi + r;
        const int gj = oj + c8;
        float* op = dout + b * HW + gi * Ww + gj;
        *(float4*)op       = make_float4(acc[0], acc[1], acc[2], acc[3]);
        *(float4*)(op + 4) = make_float4(acc[4], acc[5], acc[6], acc[7]);
    }
}

extern "C" void kernel_launch(void* const* d_in, const int* in_sizes, int n_in,
                              void* d_out, int out_size, void* d_ws, size_t ws_size,
                              hipStream_t stream) {
    const float* guidance = (const float*)d_in[0];
    const float* blur     = (const float*)d_in[1];
    const float* sparse   = (const float*)d_in[2];
    float* out = (float*)d_out;

    char* ws = (char*)d_ws;
    float* bufA = (float*)ws;
    float* bufB = bufA + NPIX;
    __half* wbuf = (__half*)(bufB + NPIX);          // NPIX*8 fp16 = 15.7 MB
    float*  cbuf = (float*)(wbuf + (size_t)NPIX * 8);

    const int threads = 256;
    const int blocks = (NPIX + threads - 1) / threads;
    affinity_norm<<<blocks, threads, 0, stream>>>(guidance, blur, sparse, wbuf, cbuf);

    // 24 steps = 3 launches x 8 fused steps
    fused_steps<<<GRID, BLOCK, 0, stream>>>(wbuf, cbuf, blur, bufA);
    fused_steps<<<GRID, BLOCK, 0, stream>>>(wbuf, cbuf, bufA, bufB);
    fused_steps<<<GRID, BLOCK, 0, stream>>>(wbuf, cbuf, bufB, out);
}

// Round 7
// 217.568 us; speedup vs baseline: 1.0923x; 1.0923x over previous
//
#include <hip/hip_runtime.h>
#include <hip/hip_fp16.h>

static constexpr int Hh = 384;
static constexpr int Ww = 1280;
static constexpr int HW = Hh * Ww;            // 491520
static constexpr int NPIX = 2 * HW;           // 983040
static constexpr int TILE = 32;               // output tile side
static constexpr int S = 8;                   // fused Jacobi steps per launch
static constexpr int R = TILE + 2 * S;        // 48 region side
static constexpr int RSTR = 50;               // LDS row stride (48 + 2 pad) -> bank spread
static constexpr int RSZ = RSTR * (R + 2) + 4;// 2504 dwords: dummy top/bottom rows + guard
static constexpr int BLOCK = 320;             // 5 waves; 288 compute threads
static constexpr int CT = 48 * 6;             // 288: one 8-px row segment each
static constexpr int TI = Hh / TILE;          // 12
static constexpr int TJ = Ww / TILE;          // 40
static constexpr int GRID = 2 * TI * TJ;      // 960 tiles
static constexpr float EPSF = 1e-9f;

// k order matches reference PADS: (di,dj) =
// k:   0       1       2       3       4       5       6       7
//    (+1,+1) (+1,0) (+1,-1) (0,+1) (0,-1) (-1,+1) (-1,0) (-1,-1)

struct WC { float4 w; float C; };

__device__ __forceinline__ WC make_wc(float v0, float v1, float v2, float v3,
                                      float v4, float v5, float v6, float v7,
                                      float a, float rawv, float sp) {
    float inv = 1.0f / a;
    v0 *= inv; v1 *= inv; v2 *= inv; v3 *= inv;
    v4 *= inv; v5 *= inv; v6 *= inv; v7 *= inv;
    float gs = v0 + v1 + v2 + v3 + v4 + v5 + v6 + v7;
    bool m = sp > 0.0f;                 // sparse >= 0 always; sign(s)==1 iff s>0
    WC o;
    o.C = m ? rawv : (1.0f - gs) * rawv;
    if (m) { v0=v1=v2=v3=v4=v5=v6=v7=0.0f; }
    o.w.x = __builtin_bit_cast(float, __floats2half2_rn(v0, v1));
    o.w.y = __builtin_bit_cast(float, __floats2half2_rn(v2, v3));
    o.w.z = __builtin_bit_cast(float, __floats2half2_rn(v4, v5));
    o.w.w = __builtin_bit_cast(float, __floats2half2_rn(v6, v7));
    return o;
}

// Precompute per pixel: 8 fp16 weights (zeroed where sparse-clamped) and
// C = m ? raw : (1-gate_sum)*raw. 4 px/thread, float4 fast path for interior.
__global__ void affinity_norm(const float* __restrict__ g,
                              const float* __restrict__ raw,
                              const float* __restrict__ sparse,
                              __half* __restrict__ wbuf,
                              float* __restrict__ cbuf) {
    const int DI[8] = { 1, 1, 1, 0, 0, -1, -1, -1 };
    const int DJ[8] = { 1, 0, -1, 1, -1, 1, 0, -1 };

    int t = blockIdx.x * blockDim.x + threadIdx.x;
    if (t >= NPIX / 4) return;
    int idx0 = t * 4;
    int b = idx0 / HW;
    int r = idx0 - b * HW;
    int i = r / Ww;
    int j0 = r - i * Ww;                       // multiple of 4
    const float* gb = g + (size_t)b * 8 * HW;
    float4* wq = (float4*)wbuf;

    if (i >= 1 && i < Hh - 1 && j0 >= 4 && j0 <= Ww - 8) {
        float vx[8], vy[8], vz[8], vw[8];
        float ax = EPSF, ay = EPSF, az = EPSF, aw = EPSF;
#pragma unroll
        for (int k = 0; k < 8; k++) {
            const float* p = gb + k * HW + (i + DI[k]) * Ww + (j0 + DJ[k]);
            float4 v = *(const float4*)p;      // 4B-aligned dwordx4 is legal
            vx[k] = v.x; vy[k] = v.y; vz[k] = v.z; vw[k] = v.w;
            ax += fabsf(v.x); ay += fabsf(v.y); az += fabsf(v.z); aw += fabsf(v.w);
        }
        float4 raw4 = *(const float4*)(raw + idx0);
        float4 sp4  = *(const float4*)(sparse + idx0);
        WC cx = make_wc(vx[0],vx[1],vx[2],vx[3],vx[4],vx[5],vx[6],vx[7], ax, raw4.x, sp4.x);
        WC cy = make_wc(vy[0],vy[1],vy[2],vy[3],vy[4],vy[5],vy[6],vy[7], ay, raw4.y, sp4.y);
        WC cz = make_wc(vz[0],vz[1],vz[2],vz[3],vz[4],vz[5],vz[6],vz[7], az, raw4.z, sp4.z);
        WC cw = make_wc(vw[0],vw[1],vw[2],vw[3],vw[4],vw[5],vw[6],vw[7], aw, raw4.w, sp4.w);
        wq[idx0]     = cx.w;
        wq[idx0 + 1] = cy.w;
        wq[idx0 + 2] = cz.w;
        wq[idx0 + 3] = cw.w;
        *(float4*)(cbuf + idx0) = make_float4(cx.C, cy.C, cz.C, cw.C);
    } else {
        for (int q = 0; q < 4; q++) {
            int idx = idx0 + q;
            int j = j0 + q;
            float v[8];
            float a = EPSF;
#pragma unroll
            for (int k = 0; k < 8; k++) {
                int ii = i + DI[k], jj = j + DJ[k];
                float gv = 0.0f;
                if (ii >= 0 && ii < Hh && jj >= 0 && jj < Ww)
                    gv = gb[k * HW + ii * Ww + jj];
                v[k] = gv;
                a += fabsf(gv);
            }
            WC c = make_wc(v[0],v[1],v[2],v[3],v[4],v[5],v[6],v[7], a, raw[idx], sparse[idx]);
            wq[idx] = c.w;
            cbuf[idx] = c.C;
        }
    }
}

// Fused S=8 Jacobi steps. Block owns 48x48 region (32x32 valid center, halo 8).
// Thread owns one 8-px row segment: d, C, fp16 weights ALL in registers for
// all steps (no address-of-register casts -> no scratch spill). LDS holds the
// published field only: stride-50 rows (bank spread), zeroed dummy border
// rows/pads keep every window value finite. Ring/OOB px: w=0, C=d0 -> they
// copy forward branchlessly.
__global__ __launch_bounds__(BLOCK) void fused_steps(
    const __half* __restrict__ wbuf, const float* __restrict__ cbuf,
    const float* __restrict__ din, float* __restrict__ dout)
{
    __shared__ __align__(16) float sd[2 * RSZ];

    const int tid = threadIdx.x;
    int bx = blockIdx.x;
    const int tj = bx % TJ; bx /= TJ;
    const int ti = bx % TI;
    const int b  = bx / TI;
    const int oi = ti * TILE - S;
    const int oj = tj * TILE - S;

    // zero both buffers: guards, pads, dummy rows must be finite forever
    for (int p = tid; p < 2 * RSZ; p += BLOCK) sd[p] = 0.0f;
    __syncthreads();

    const bool active = tid < CT;
    const int r  = active ? tid / 6 : 0;        // region row 0..47
    const int c8 = active ? (tid % 6) * 8 : 0;  // segment start col
    const int rowO = RSTR * (r + 1) + 2 + c8;   // own row base (+2 front guard)
    const int rowA = rowO - RSTR;               // row above
    const int rowB = rowO + RSTR;               // row below

    float d[8], C[8];
    __half2 w01[8], w23[8], w45[8], w67[8];

    if (active) {
        const int gi  = oi + r;
        const int gic = min(max(gi, 0), Hh - 1);
        const bool rring = (r == 0) | (r == R - 1) | (gi != gic);
#pragma unroll
        for (int i = 0; i < 8; i++) {
            const int c   = c8 + i;
            const int gj  = oj + c;
            const int gjc = min(max(gj, 0), Ww - 1);
            const int idx = b * HW + gic * Ww + gjc;
            float dv = din[idx];
            d[i] = dv;
            const bool ring = rring | (c == 0) | (c == R - 1) | (gj != gjc);
            float4 wv = ((const float4*)wbuf)[idx];
            if (ring) wv = make_float4(0.f, 0.f, 0.f, 0.f);
            C[i] = ring ? dv : cbuf[idx];
            w01[i] = __builtin_bit_cast(__half2, wv.x);
            w23[i] = __builtin_bit_cast(__half2, wv.y);
            w45[i] = __builtin_bit_cast(__half2, wv.z);
            w67[i] = __builtin_bit_cast(__half2, wv.w);
        }
        *(float2*)&sd[rowO]     = make_float2(d[0], d[1]);
        *(float2*)&sd[rowO + 2] = make_float2(d[2], d[3]);
        *(float2*)&sd[rowO + 4] = make_float2(d[4], d[5]);
        *(float2*)&sd[rowO + 6] = make_float2(d[6], d[7]);
    }
    __syncthreads();

    int cur = 0;
    for (int s = 1; s < S; s++) {
        const float* s0 = sd + cur * RSZ;
        float* s1 = sd + (cur ^ 1) * RSZ;
        if (active) {
            float a[10], e[10];
            a[0] = s0[rowA - 1];
            { float2 t0 = *(const float2*)&s0[rowA];
              float2 t1 = *(const float2*)&s0[rowA + 2];
              float2 t2 = *(const float2*)&s0[rowA + 4];
              float2 t3 = *(const float2*)&s0[rowA + 6];
              a[1]=t0.x; a[2]=t0.y; a[3]=t1.x; a[4]=t1.y;
              a[5]=t2.x; a[6]=t2.y; a[7]=t3.x; a[8]=t3.y; }
            a[9] = s0[rowA + 8];
            e[0] = s0[rowB - 1];
            { float2 t0 = *(const float2*)&s0[rowB];
              float2 t1 = *(const float2*)&s0[rowB + 2];
              float2 t2 = *(const float2*)&s0[rowB + 4];
              float2 t3 = *(const float2*)&s0[rowB + 6];
              e[1]=t0.x; e[2]=t0.y; e[3]=t1.x; e[4]=t1.y;
              e[5]=t2.x; e[6]=t2.y; e[7]=t3.x; e[8]=t3.y; }
            e[9] = s0[rowB + 8];
            float lft = s0[rowO - 1];
            float rgt = s0[rowO + 8];

            float nd[8];
#pragma unroll
            for (int i = 0; i < 8; i++) {
                float lv = (i == 0) ? lft : d[i - 1];
                float rv = (i == 7) ? rgt : d[i + 1];
                nd[i] = C[i]
                    + __half2float(w01[i].x) * e[i + 2] + __half2float(w01[i].y) * e[i + 1]
                    + __half2float(w23[i].x) * e[i]     + __half2float(w23[i].y) * rv
                    + __half2float(w45[i].x) * lv       + __half2float(w45[i].y) * a[i + 2]
                    + __half2float(w67[i].x) * a[i + 1] + __half2float(w67[i].y) * a[i];
            }
#pragma unroll
            for (int i = 0; i < 8; i++) d[i] = nd[i];
            *(float2*)&s1[rowO]     = make_float2(d[0], d[1]);
            *(float2*)&s1[rowO + 2] = make_float2(d[2], d[3]);
            *(float2*)&s1[rowO + 4] = make_float2(d[4], d[5]);
            *(float2*)&s1[rowO + 6] = make_float2(d[6], d[7]);
        }
        __syncthreads();
        cur ^= 1;
    }

    // final step: valid 32x32 center only, straight to global
    if (active && r >= S && r < R - S && c8 >= 8 && c8 <= 32) {
        const float* s0 = sd + cur * RSZ;
        float a[10], e[10];
        a[0] = s0[rowA - 1];
        { float2 t0 = *(const float2*)&s0[rowA];
          float2 t1 = *(const float2*)&s0[rowA + 2];
          float2 t2 = *(const float2*)&s0[rowA + 4];
          float2 t3 = *(const float2*)&s0[rowA + 6];
          a[1]=t0.x; a[2]=t0.y; a[3]=t1.x; a[4]=t1.y;
          a[5]=t2.x; a[6]=t2.y; a[7]=t3.x; a[8]=t3.y; }
        a[9] = s0[rowA + 8];
        e[0] = s0[rowB - 1];
        { float2 t0 = *(const float2*)&s0[rowB];
          float2 t1 = *(const float2*)&s0[rowB + 2];
          float2 t2 = *(const float2*)&s0[rowB + 4];
          float2 t3 = *(const float2*)&s0[rowB + 6];
          e[1]=t0.x; e[2]=t0.y; e[3]=t1.x; e[4]=t1.y;
          e[5]=t2.x; e[6]=t2.y; e[7]=t3.x; e[8]=t3.y; }
        e[9] = s0[rowB + 8];
        float lft = s0[rowO - 1];
        float rgt = s0[rowO + 8];

        float nd[8];
#pragma unroll
        for (int i = 0; i < 8; i++) {
            float lv = (i == 0) ? lft : d[i - 1];
            float rv = (i == 7) ? rgt : d[i + 1];
            nd[i] = C[i]
                + __half2float(w01[i].x) * e[i + 2] + __half2float(w01[i].y) * e[i + 1]
                + __half2float(w23[i].x) * e[i]     + __half2float(w23[i].y) * rv
                + __half2float(w45[i].x) * lv       + __half2float(w45[i].y) * a[i + 2]
                + __half2float(w67[i].x) * a[i + 1] + __half2float(w67[i].y) * a[i];
        }
        const int gi = oi + r, gj = oj + c8;
        float* op = dout + b * HW + gi * Ww + gj;
        *(float4*)op       = make_float4(nd[0], nd[1], nd[2], nd[3]);
        *(float4*)(op + 4) = make_float4(nd[4], nd[5], nd[6], nd[7]);
    }
}

extern "C" void kernel_launch(void* const* d_in, const int* in_sizes, int n_in,
                              void* d_out, int out_size, void* d_ws, size_t ws_size,
                              hipStream_t stream) {
    const float* guidance = (const float*)d_in[0];
    const float* blur     = (const float*)d_in[1];
    const float* sparse   = (const float*)d_in[2];
    float* out = (float*)d_out;

    char* ws = (char*)d_ws;
    float* bufA = (float*)ws;
    float* bufB = bufA + NPIX;
    __half* wbuf = (__half*)(bufB + NPIX);          // NPIX*8 fp16 = 15.7 MB
    float*  cbuf = (float*)(wbuf + (size_t)NPIX * 8);

    affinity_norm<<<NPIX / 4 / 256, 256, 0, stream>>>(guidance, blur, sparse, wbuf, cbuf);

    // 24 steps = 3 launches x 8 fused steps
    fused_steps<<<GRID, BLOCK, 0, stream>>>(wbuf, cbuf, blur, bufA);
    fused_steps<<<GRID, BLOCK, 0, stream>>>(wbuf, cbuf, bufA, bufB);
    fused_steps<<<GRID, BLOCK, 0, stream>>>(wbuf, cbuf, bufB, out);
}

// Round 8
// 187.292 us; speedup vs baseline: 1.2689x; 1.1617x over previous
//
#include <hip/hip_runtime.h>
#include <hip/hip_fp16.h>

static constexpr int Hh = 384;
static constexpr int Ww = 1280;
static constexpr int HW = Hh * Ww;            // 491520
static constexpr int NPIX = 2 * HW;           // 983040
static constexpr int TILE = 32;               // output tile side
static constexpr int S = 8;                   // fused Jacobi steps per launch
static constexpr int R = TILE + 2 * S;        // 48 region side
static constexpr int RR = R * R;              // 2304
static constexpr int G = R + 1;               // 49: guard ring (covers p +/- 49)
static constexpr int LBUF = RR + 2 * G + 2;   // 2404 dwords per buffer
static constexpr int BLOCK = 256;             // 4 waves; 9 px/thread (256*9=2304)
static constexpr int PPT = 9;
static constexpr int TI = Hh / TILE;          // 12
static constexpr int TJ = Ww / TILE;          // 40
static constexpr int GRID = 2 * TI * TJ;      // 960 tiles
static constexpr float EPSF = 1e-9f;

// k order matches reference PADS: (di,dj) =
// k:   0       1       2       3       4       5       6       7
//    (+1,+1) (+1,0) (+1,-1) (0,+1) (0,-1) (-1,+1) (-1,0) (-1,-1)
// region-index offset = di*R + dj.

__device__ __forceinline__ void pack_wc(const float v[8], float a, float rawv,
                                        float sp, float4* wout, float* Cout) {
    float inv = 1.0f / a;
    float w0 = v[0]*inv, w1 = v[1]*inv, w2 = v[2]*inv, w3 = v[3]*inv;
    float w4 = v[4]*inv, w5 = v[5]*inv, w6 = v[6]*inv, w7 = v[7]*inv;
    float gs = w0 + w1 + w2 + w3 + w4 + w5 + w6 + w7;
    bool m = sp > 0.0f;                 // sparse >= 0 always; sign(s)==1 iff s>0
    *Cout = m ? rawv : (1.0f - gs) * rawv;
    if (m) { w0=w1=w2=w3=w4=w5=w6=w7=0.0f; }
    float4 w;
    w.x = __builtin_bit_cast(float, __floats2half2_rn(w0, w1));
    w.y = __builtin_bit_cast(float, __floats2half2_rn(w2, w3));
    w.z = __builtin_bit_cast(float, __floats2half2_rn(w4, w5));
    w.w = __builtin_bit_cast(float, __floats2half2_rn(w6, w7));
    *wout = w;
}

// 4 px/thread. Interior fast path: per channel one ALIGNED float4 + at most
// one edge scalar (shift in registers) — no unaligned dwordx4.
__global__ void affinity_norm(const float* __restrict__ g,
                              const float* __restrict__ raw,
                              const float* __restrict__ sparse,
                              __half* __restrict__ wbuf,
                              float* __restrict__ cbuf) {
    const int DI[8] = { 1, 1, 1, 0, 0, -1, -1, -1 };
    const int DJ[8] = { 1, 0, -1, 1, -1, 1, 0, -1 };

    int t = blockIdx.x * blockDim.x + threadIdx.x;
    if (t >= NPIX / 4) return;
    int idx0 = t * 4;
    int b = idx0 / HW;
    int r = idx0 - b * HW;
    int i = r / Ww;
    int j0 = r - i * Ww;                       // multiple of 4
    const float* gb = g + (size_t)b * 8 * HW;
    float4* wq = (float4*)wbuf;

    if (i >= 1 && i < Hh - 1 && j0 >= 4 && j0 <= Ww - 8) {
        float vv[4][8];                        // [pixel][channel]
        float acc[4] = { EPSF, EPSF, EPSF, EPSF };
#pragma unroll
        for (int k = 0; k < 8; k++) {
            const float* rowp = gb + k * HW + (i + DI[k]) * Ww;
            float4 v = *(const float4*)(rowp + j0);    // 16B-aligned
            float e0, e1, e2, e3;
            if (DJ[k] == 0)      { e0 = v.x; e1 = v.y; e2 = v.z; e3 = v.w; }
            else if (DJ[k] == 1) { float s = rowp[j0 + 4]; e0 = v.y; e1 = v.z; e2 = v.w; e3 = s; }
            else                 { float s = rowp[j0 - 1]; e0 = s;   e1 = v.x; e2 = v.y; e3 = v.z; }
            vv[0][k] = e0; vv[1][k] = e1; vv[2][k] = e2; vv[3][k] = e3;
            acc[0] += fabsf(e0); acc[1] += fabsf(e1);
            acc[2] += fabsf(e2); acc[3] += fabsf(e3);
        }
        float4 raw4 = *(const float4*)(raw + idx0);
        float4 sp4  = *(const float4*)(sparse + idx0);
        float4 w0, w1, w2, w3;
        float  c0, c1, c2, c3;
        pack_wc(vv[0], acc[0], raw4.x, sp4.x, &w0, &c0);
        pack_wc(vv[1], acc[1], raw4.y, sp4.y, &w1, &c1);
        pack_wc(vv[2], acc[2], raw4.z, sp4.z, &w2, &c2);
        pack_wc(vv[3], acc[3], raw4.w, sp4.w, &w3, &c3);
        wq[idx0]     = w0;
        wq[idx0 + 1] = w1;
        wq[idx0 + 2] = w2;
        wq[idx0 + 3] = w3;
        *(float4*)(cbuf + idx0) = make_float4(c0, c1, c2, c3);
    } else {
        for (int q = 0; q < 4; q++) {
            int idx = idx0 + q;
            int j = j0 + q;
            float v[8];
            float a = EPSF;
#pragma unroll
            for (int k = 0; k < 8; k++) {
                int ii = i + DI[k], jj = j + DJ[k];
                float gv = 0.0f;
                if (ii >= 0 && ii < Hh && jj >= 0 && jj < Ww)
                    gv = gb[k * HW + ii * Ww + jj];
                v[k] = gv;
                a += fabsf(gv);
            }
            float4 w; float c;
            pack_wc(v, a, raw[idx], sparse[idx], &w, &c);
            wq[idx] = w;
            cbuf[idx] = c;
        }
    }
}

// Fused S=8 Jacobi steps, 48x48 region (32x32 valid center, halo 8).
// Lane-contiguous pixel ownership: thread owns 9 px at p = tid + q*256 in a
// FLAT region buffer -> every LDS access is lane-consecutive (2/bank = free,
// per r5's measured 0 conflicts). w (fp16x8 packed) + C live in registers for
// all steps. Guard rings are zeroed; ring/OOB px get w=0, C=d0 -> copy
// forward branchlessly.
__global__ __launch_bounds__(BLOCK) void fused_steps(
    const __half* __restrict__ wbuf, const float* __restrict__ cbuf,
    const float* __restrict__ din, float* __restrict__ dout)
{
    __shared__ float sd[2][LBUF];

    const int tid = threadIdx.x;
    int bx = blockIdx.x;
    const int tj = bx % TJ; bx /= TJ;
    const int ti = bx % TI;
    const int b  = bx / TI;
    const int oi = ti * TILE - S;
    const int oj = tj * TILE - S;

    // zero guard words of both buffers (never written afterwards)
    for (int p = tid; p < LBUF; p += BLOCK) {
        if (p < G || p >= G + RR) { sd[0][p] = 0.0f; sd[1][p] = 0.0f; }
    }

    float  C[PPT];
    float4 wv[PPT];

#pragma unroll
    for (int q = 0; q < PPT; q++) {
        const int prr = tid + q * BLOCK;       // 0..2303, lane-contiguous
        const int rr = prr / R;
        const int cc = prr - rr * R;
        const int gi = oi + rr, gj = oj + cc;
        const int gic = min(max(gi, 0), Hh - 1);
        const int gjc = min(max(gj, 0), Ww - 1);
        const int idx = b * HW + gic * Ww + gjc;
        const float dv = din[idx];
        const bool ring = (rr == 0) | (rr == R - 1) | (cc == 0) | (cc == R - 1)
                        | (gi != gic) | (gj != gjc);
        float4 w = ((const float4*)wbuf)[idx];
        if (ring) w = make_float4(0.f, 0.f, 0.f, 0.f);
        wv[q] = w;
        C[q] = ring ? dv : cbuf[idx];
        sd[0][G + prr] = dv;
    }
    __syncthreads();

    int cur = 0;
    for (int s = 1; s < S; s++) {
        const float* s0 = sd[cur];
        float* s1 = sd[cur ^ 1];
#pragma unroll
        for (int q = 0; q < PPT; q++) {
            const int p = G + tid + q * BLOCK;
            const __half2 w01 = __builtin_bit_cast(__half2, wv[q].x);
            const __half2 w23 = __builtin_bit_cast(__half2, wv[q].y);
            const __half2 w45 = __builtin_bit_cast(__half2, wv[q].z);
            const __half2 w67 = __builtin_bit_cast(__half2, wv[q].w);
            float nd = C[q]
                + __half2float(w01.x) * s0[p + R + 1] + __half2float(w01.y) * s0[p + R]
                + __half2float(w23.x) * s0[p + R - 1] + __half2float(w23.y) * s0[p + 1]
                + __half2float(w45.x) * s0[p - 1]     + __half2float(w45.y) * s0[p - R + 1]
                + __half2float(w67.x) * s0[p - R]     + __half2float(w67.y) * s0[p - R - 1];
            s1[p] = nd;
        }
        __syncthreads();
        cur ^= 1;
    }

    // final step: valid 32x32 center only, straight to global
    const float* s0 = sd[cur];
#pragma unroll
    for (int q = 0; q < PPT; q++) {
        const int prr = tid + q * BLOCK;
        const int rr = prr / R;
        const int cc = prr - rr * R;
        if (rr >= S && rr < R - S && cc >= S && cc < R - S) {
            const int p = G + prr;
            const __half2 w01 = __builtin_bit_cast(__half2, wv[q].x);
            const __half2 w23 = __builtin_bit_cast(__half2, wv[q].y);
            const __half2 w45 = __builtin_bit_cast(__half2, wv[q].z);
            const __half2 w67 = __builtin_bit_cast(__half2, wv[q].w);
            float nd = C[q]
                + __half2float(w01.x) * s0[p + R + 1] + __half2float(w01.y) * s0[p + R]
                + __half2float(w23.x) * s0[p + R - 1] + __half2float(w23.y) * s0[p + 1]
                + __half2float(w45.x) * s0[p - 1]     + __half2float(w45.y) * s0[p - R + 1]
                + __half2float(w67.x) * s0[p - R]     + __half2float(w67.y) * s0[p - R - 1];
            dout[b * HW + (oi + rr) * Ww + (oj + cc)] = nd;
        }
    }
}

extern "C" void kernel_launch(void* const* d_in, const int* in_sizes, int n_in,
                              void* d_out, int out_size, void* d_ws, size_t ws_size,
                              hipStream_t stream) {
    const float* guidance = (const float*)d_in[0];
    const float* blur     = (const float*)d_in[1];
    const float* sparse   = (const float*)d_in[2];
    float* out = (float*)d_out;

    char* ws = (char*)d_ws;
    float* bufA = (float*)ws;
    float* bufB = bufA + NPIX;
    __half* wbuf = (__half*)(bufB + NPIX);          // NPIX*8 fp16 = 15.7 MB
    float*  cbuf = (float*)(wbuf + (size_t)NPIX * 8);

    affinity_norm<<<NPIX / 4 / 256, 256, 0, stream>>>(guidance, blur, sparse, wbuf, cbuf);

    // 24 steps = 3 launches x 8 fused steps
    fused_steps<<<GRID, BLOCK, 0, stream>>>(wbuf, cbuf, blur, bufA);
    fused_steps<<<GRID, BLOCK, 0, stream>>>(wbuf, cbuf, bufA, bufB);
    fused_steps<<<GRID, BLOCK, 0, stream>>>(wbuf, cbuf, bufB, out);
}